// Round 1
// baseline (15206.764 us; speedup 1.0000x reference)
//
#include <hip/hip_runtime.h>

#define TT 336
#define BB 256
#define DD 128
#define HH 1024
#define GG 4096   // 4*H

typedef __attribute__((ext_vector_type(8))) short short8;
typedef __attribute__((ext_vector_type(8))) unsigned short ushort8;
typedef __attribute__((ext_vector_type(4))) unsigned short ushort4v;
typedef __attribute__((ext_vector_type(4))) float floatx4;

// ---- workspace layout (bytes) ----
#define OFF_C1  0u            // 256*1024 f32   = 1 MB
#define OFF_C2  1048576u      // 1 MB
#define OFF_H1  2097152u      // 256*1024 bf16  = 512 KB
#define OFF_H2  2621440u      // 512 KB
#define OFF_Z1  3145728u      // 256*4096 f32   = 4 MB
#define OFF_Z2  7340032u      // 4 MB
#define OFF_X   11534336u     // 256*336*128 bf16 = 22020096 B
#define OFF_W1T 33554432u     // 4096*1152 bf16 = 9437184 B
#define OFF_W2T 42991616u     // 4096*2048 bf16 = 16777216 B
// end = 59768832

static __device__ __forceinline__ unsigned short f2bf(float f) {
  unsigned int x = __float_as_uint(f);
  x += 0x7fffu + ((x >> 16) & 1u);   // RNE
  return (unsigned short)(x >> 16);
}
static __device__ __forceinline__ float bf2f(unsigned short u) {
  return __uint_as_float(((unsigned int)u) << 16);
}
static __device__ __forceinline__ float sigm(float x) {
  return 1.f / (1.f + __expf(-x));
}
static __device__ __forceinline__ float tanh_fast(float x) {
  float ax = fabsf(x);
  float e = __expf(-2.f * ax);
  float t = (1.f - e) / (1.f + e);
  return x < 0.f ? -t : t;
}

#define GLOAD_LDS16(gsrc, ldst)                                              \
  __builtin_amdgcn_global_load_lds(                                          \
      (const __attribute__((address_space(1))) void*)(gsrc),                 \
      (__attribute__((address_space(3))) void*)(ldst), 16, 0, 0)

// ---------------- init: zero c1,c2,h1,h2 (3 MB contiguous) + d_out ----------
__global__ __launch_bounds__(256) void init_zero(float* out, uint4* span, long n16) {
  long i = (long)blockIdx.x * 256 + threadIdx.x;
  if (i < n16) span[i] = make_uint4(0u, 0u, 0u, 0u);
  if (i == 0) out[0] = 0.f;
}

// ---------------- features fp32 -> bf16 ----------------
__global__ __launch_bounds__(256) void feat2bf(const float* __restrict__ in,
                                               unsigned short* __restrict__ out, long n8) {
  long i = (long)blockIdx.x * 256 + threadIdx.x;
  if (i >= n8) return;
  const floatx4* p = (const floatx4*)(in + i * 8);
  floatx4 a = p[0], b = p[1];
  ushort8 v;
  #pragma unroll
  for (int c = 0; c < 4; ++c) { v[c] = f2bf(a[c]); v[4 + c] = f2bf(b[c]); }
  *(ushort8*)(out + i * 8) = v;
}

// ------- transpose W (K x 4096 f32) -> WT (4096 x K bf16), quad-XOR swizzled -
// WT row n: actual 16B-quad q stored at position (q & ~7) | ((q ^ n) & 7)
__global__ __launch_bounds__(256) void transpose_swz(const float* __restrict__ W,
                                                     unsigned short* __restrict__ out, int K) {
  __shared__ unsigned short tile[64 * 65];
  int tid = threadIdx.x;
  int ktiles = K >> 6;
  int kt = blockIdx.x % ktiles;
  int nt = blockIdx.x / ktiles;
  #pragma unroll
  for (int i = 0; i < 16; ++i) {
    int lin = i * 256 + tid;
    int lk = lin >> 6, nn = lin & 63;
    tile[lk * 65 + nn] = f2bf(W[(size_t)(kt * 64 + lk) * GG + nt * 64 + nn]);
  }
  __syncthreads();
  #pragma unroll
  for (int it = 0; it < 2; ++it) {
    int idx = it * 256 + tid;
    int nl = idx >> 3, ql = idx & 7;
    int n = nt * 64 + nl;
    ushort8 v;
    #pragma unroll
    for (int j = 0; j < 8; ++j) v[j] = tile[(ql * 8 + j) * 65 + nl];
    size_t off = (size_t)n * K + (size_t)((kt * 8 + (ql ^ (n & 7))) << 3);
    *(ushort8*)(out + off) = v;
  }
}

// ---------------- fused-phase GEMM: z = [Aa|Ab] @ WT^T ----------------
// layer0: z1(t)= [x(t)|h1] @ W1 ; layer1: z2(t-1) = [h1|h2] @ W2
// 128 blocks: bid>>6 = layer, 2 m-tiles x 32 n-tiles of 128x128.
__global__ __launch_bounds__(256) void gemm_phase(
    const unsigned short* __restrict__ Xbf, const unsigned short* __restrict__ h1,
    const unsigned short* __restrict__ h2, const unsigned short* __restrict__ WT1,
    const unsigned short* __restrict__ WT2, float* __restrict__ z1,
    float* __restrict__ z2, int t, int do1, int do2) {
  __shared__ __align__(16) unsigned short Alds[128 * 64];  // 16 KB, row=128B swizzled
  __shared__ __align__(16) unsigned short Blds[128 * 64];  // 16 KB

  int bid = blockIdx.x;
  int layer = bid >> 6;
  if (layer == 0 && !do1) return;
  if (layer == 1 && !do2) return;
  int r = bid & 63;
  int mtile = r & 1;
  int n0 = (r >> 1) * 128;

  const unsigned short *Aa, *Ab, *Bw;
  float* z;
  size_t strideAa;
  int Ka, K;
  if (layer == 0) {
    Aa = Xbf + (size_t)t * DD; strideAa = (size_t)TT * DD; Ka = DD;
    Ab = h1; Bw = WT1; K = DD + HH; z = z1;
  } else {
    Aa = h1; strideAa = HH; Ka = HH;
    Ab = h2; Bw = WT2; K = 2 * HH; z = z2;
  }

  int tid = threadIdx.x;
  int w = tid >> 6, lane = tid & 63;
  int wm = w >> 1, wn = w & 1;

  floatx4 acc[4][4];
  #pragma unroll
  for (int i = 0; i < 4; ++i)
    #pragma unroll
    for (int j = 0; j < 4; ++j) acc[i][j] = (floatx4){0.f, 0.f, 0.f, 0.f};

  for (int k0 = 0; k0 < K; k0 += 64) {
    // ---- stage B via async global->LDS (source is pre-swizzled) ----
    #pragma unroll
    for (int c = 0; c < 4; ++c) {
      int nl = w * 32 + c * 8 + (lane >> 3);
      const unsigned short* src = Bw + (size_t)(n0 + nl) * K + k0 + (lane & 7) * 8;
      unsigned short* dst = &Blds[(w * 32 + c * 8) * 64];
      GLOAD_LDS16(src, dst);
    }
    // ---- stage A explicitly, swizzling quads ----
    #pragma unroll
    for (int pass = 0; pass < 4; ++pass) {
      int ml = pass * 32 + (tid >> 3);
      int q = tid & 7;
      int kk = k0 + q * 8;
      int mg = mtile * 128 + ml;
      const unsigned short* src = (kk < Ka) ? (Aa + (size_t)mg * strideAa + kk)
                                            : (Ab + (size_t)mg * HH + (kk - Ka));
      ushort8 v = *(const ushort8*)src;
      *(ushort8*)&Alds[ml * 64 + ((q ^ (ml & 7)) << 3)] = v;
    }
    __syncthreads();
    // ---- compute: 2 k-steps of 32, 4x4 MFMA 16x16x32 per wave ----
    #pragma unroll
    for (int ks = 0; ks < 2; ++ks) {
      short8 af[4], bfr[4];
      int qb = ks * 4 + (lane >> 4);
      #pragma unroll
      for (int mi = 0; mi < 4; ++mi) {
        int ml = wm * 64 + mi * 16 + (lane & 15);
        af[mi] = *(const short8*)&Alds[ml * 64 + ((qb ^ (ml & 7)) << 3)];
      }
      #pragma unroll
      for (int ni = 0; ni < 4; ++ni) {
        int nl = wn * 64 + ni * 16 + (lane & 15);
        bfr[ni] = *(const short8*)&Blds[nl * 64 + ((qb ^ (nl & 7)) << 3)];
      }
      #pragma unroll
      for (int mi = 0; mi < 4; ++mi)
        #pragma unroll
        for (int ni = 0; ni < 4; ++ni)
          acc[mi][ni] = __builtin_amdgcn_mfma_f32_16x16x32_bf16(af[mi], bfr[ni],
                                                                acc[mi][ni], 0, 0, 0);
    }
    __syncthreads();
  }
  // ---- epilogue: C/D layout col=lane&15, row=(lane>>4)*4+r ----
  #pragma unroll
  for (int mi = 0; mi < 4; ++mi)
    #pragma unroll
    for (int ni = 0; ni < 4; ++ni)
      #pragma unroll
      for (int rr = 0; rr < 4; ++rr) {
        int row = mtile * 128 + wm * 64 + mi * 16 + (lane >> 4) * 4 + rr;
        int col = n0 + wn * 64 + ni * 16 + (lane & 15);
        z[(size_t)row * GG + col] = acc[mi][ni][rr];
      }
}

// ---------------- cell nonlinearity ----------------
static __device__ __forceinline__ void cell_one(const float* __restrict__ z,
                                                const float* __restrict__ bias,
                                                float* __restrict__ cst,
                                                unsigned short* __restrict__ hst,
                                                int b, int j) {
  floatx4 zi = *(const floatx4*)&z[(size_t)b * GG + j];
  floatx4 zj = *(const floatx4*)&z[(size_t)b * GG + HH + j];
  floatx4 zf = *(const floatx4*)&z[(size_t)b * GG + 2 * HH + j];
  floatx4 zo = *(const floatx4*)&z[(size_t)b * GG + 3 * HH + j];
  floatx4 bi = *(const floatx4*)&bias[j];
  floatx4 bj = *(const floatx4*)&bias[HH + j];
  floatx4 bv = *(const floatx4*)&bias[2 * HH + j];
  floatx4 bo = *(const floatx4*)&bias[3 * HH + j];
  floatx4 c = *(const floatx4*)&cst[(size_t)b * HH + j];
  floatx4 cn;
  ushort4v hv;
  #pragma unroll
  for (int q = 0; q < 4; ++q) {
    float i_ = zi[q] + bi[q];
    float j_ = zj[q] + bj[q];
    float f_ = zf[q] + bv[q] + 1.f;   // FORGET_BIAS
    float o_ = zo[q] + bo[q];
    float nc = c[q] * sigm(f_) + sigm(i_) * tanh_fast(j_);
    cn[q] = nc;
    hv[q] = f2bf(tanh_fast(nc) * sigm(o_));
  }
  *(floatx4*)&cst[(size_t)b * HH + j] = cn;
  *(ushort4v*)&hst[(size_t)b * HH + j] = hv;
}

__global__ __launch_bounds__(256) void cell_phase(
    const float* __restrict__ z1, const float* __restrict__ z2,
    const float* __restrict__ b1, const float* __restrict__ b2,
    float* __restrict__ c1, float* __restrict__ c2,
    unsigned short* __restrict__ h1, unsigned short* __restrict__ h2,
    int do1, int do2) {
  int b = blockIdx.x;
  int j = threadIdx.x * 4;
  if (do1) cell_one(z1, b1, c1, h1, b, j);
  if (do2) cell_one(z2, b2, c2, h2, b, j);
}

// ---------------- dense head + MSE loss ----------------
__global__ __launch_bounds__(64) void head_loss(const unsigned short* __restrict__ h2,
                                                const float* __restrict__ Wd,
                                                const float* __restrict__ bd,
                                                const float* __restrict__ labels,
                                                float* __restrict__ out) {
  int b = blockIdx.x;
  int l = threadIdx.x;
  float p[24];
  #pragma unroll
  for (int n = 0; n < 24; ++n) p[n] = 0.f;
  for (int k = l; k < HH; k += 64) {
    float hv = bf2f(h2[(size_t)b * HH + k]);
    const float* wr = Wd + (size_t)k * 24;
    #pragma unroll
    for (int n = 0; n < 24; ++n) p[n] += hv * wr[n];
  }
  #pragma unroll
  for (int n = 0; n < 24; ++n) {
    float v = p[n];
    for (int off = 32; off > 0; off >>= 1) v += __shfl_down(v, off);
    p[n] = v;
  }
  if (l == 0) {
    float s = 0.f;
    #pragma unroll
    for (int n = 0; n < 24; ++n) {
      float pred = p[n] + bd[n];
      float d = pred - labels[b * 24 + n];
      s += d * d;
    }
    atomicAdd(out, s * (1.0f / 6144.0f));
  }
}

extern "C" void kernel_launch(void* const* d_in, const int* in_sizes, int n_in,
                              void* d_out, int out_size, void* d_ws, size_t ws_size,
                              hipStream_t stream) {
  const float* features = (const float*)d_in[0];
  const float* labels   = (const float*)d_in[1];
  const float* W1 = (const float*)d_in[2];
  const float* b1 = (const float*)d_in[3];
  const float* W2 = (const float*)d_in[4];
  const float* b2 = (const float*)d_in[5];
  const float* Wd = (const float*)d_in[6];
  const float* bd = (const float*)d_in[7];

  char* ws = (char*)d_ws;
  float*          c1  = (float*)(ws + OFF_C1);
  float*          c2  = (float*)(ws + OFF_C2);
  unsigned short* h1  = (unsigned short*)(ws + OFF_H1);
  unsigned short* h2  = (unsigned short*)(ws + OFF_H2);
  float*          z1  = (float*)(ws + OFF_Z1);
  float*          z2  = (float*)(ws + OFF_Z2);
  unsigned short* Xbf = (unsigned short*)(ws + OFF_X);
  unsigned short* WT1 = (unsigned short*)(ws + OFF_W1T);
  unsigned short* WT2 = (unsigned short*)(ws + OFF_W2T);
  float* out = (float*)d_out;

  // state + out zero-init (ws/out are poisoned before every launch)
  init_zero<<<768, 256, 0, stream>>>(out, (uint4*)ws, 196608L);
  // features -> bf16 (11,010,048 elems / 8 per thread)
  feat2bf<<<5376, 256, 0, stream>>>(features, Xbf, 1376256L);
  // weights -> transposed + swizzled bf16
  transpose_swz<<<18 * 64, 256, 0, stream>>>(W1, WT1, DD + HH);
  transpose_swz<<<32 * 64, 256, 0, stream>>>(W2, WT2, 2 * HH);

  // phases: p computes z1(t=p) [if p<T] and z2(t=p-1) [if p>=1]
  for (int p = 0; p <= TT; ++p) {
    int do1 = (p < TT) ? 1 : 0;
    int do2 = (p >= 1) ? 1 : 0;
    gemm_phase<<<128, 256, 0, stream>>>(Xbf, h1, h2, WT1, WT2, z1, z2, p, do1, do2);
    cell_phase<<<256, 256, 0, stream>>>(z1, z2, b1, b2, c1, c2, h1, h2, do1, do2);
  }
  head_loss<<<256, 64, 0, stream>>>(h2, Wd, bd, labels, out);
}

// Round 2
// 8111.427 us; speedup vs baseline: 1.8747x; 1.8747x over previous
//
#include <hip/hip_runtime.h>

#define TT 336
#define BB 256
#define DD 128
#define HH 1024
#define TD 43008   // T*D

typedef __attribute__((ext_vector_type(8))) short short8;
typedef __attribute__((ext_vector_type(8))) unsigned short ushort8;
typedef __attribute__((ext_vector_type(4))) float floatx4;

// ---- workspace layout (bytes) ----
#define OFF_C1  0u            // 256*1024 f32 = 1 MB
#define OFF_C2  1048576u      // 1 MB
#define OFF_H1  2097152u      // 2 bufs x 512 KB (bf16, swizzled)
#define OFF_H2  3145728u      // 2 bufs x 512 KB
#define OFF_B1P 4194304u      // 4096 f32 permuted bias
#define OFF_B2P 4210688u
#define OFF_X   4227072u      // 256*336*128 bf16 swizzled = 22020096
#define OFF_W1T 26247168u     // 4096*1152 bf16 = 9437184
#define OFF_W2T 35684352u     // 4096*2048 bf16 = 16777216
// end = 52461568

static __device__ __forceinline__ unsigned short f2bf(float f) {
  unsigned int x = __float_as_uint(f);
  x += 0x7fffu + ((x >> 16) & 1u);   // RNE
  return (unsigned short)(x >> 16);
}
static __device__ __forceinline__ float bf2f(unsigned short u) {
  return __uint_as_float(((unsigned int)u) << 16);
}
static __device__ __forceinline__ float sigm(float x) {
  return 1.f / (1.f + __expf(-x));
}
static __device__ __forceinline__ float tanh_fast(float x) {
  float ax = fabsf(x);
  float e = __expf(-2.f * ax);
  float t = (1.f - e) / (1.f + e);
  return x < 0.f ? -t : t;
}

#define GLOAD_LDS16(gsrc, ldst)                                              \
  __builtin_amdgcn_global_load_lds(                                          \
      (const __attribute__((address_space(1))) void*)(gsrc),                 \
      (__attribute__((address_space(3))) void*)(ldst), 16, 0, 0)

// ---------------- init: zero c1,c2,h1x2,h2x2 (4 MB) + d_out ----------------
__global__ __launch_bounds__(256) void init_zero(float* out, uint4* span, long n16) {
  long i = (long)blockIdx.x * 256 + threadIdx.x;
  if (i < n16) span[i] = make_uint4(0u, 0u, 0u, 0u);
  if (i == 0) out[0] = 0.f;
}

// ------- features fp32 -> bf16, quad-swizzled by batch row ----------------
// quad Q (8 elems); row b = Q/5376; stored at (Q&~7)|((Q^b)&7)
__global__ __launch_bounds__(256) void feat2bf(const float* __restrict__ in,
                                               unsigned short* __restrict__ out, long nq) {
  long Q = (long)blockIdx.x * 256 + threadIdx.x;
  if (Q >= nq) return;
  int b = (int)(Q / 5376);
  long outQ = (Q & ~7L) | ((Q ^ (long)b) & 7);
  const floatx4* pp = (const floatx4*)(in + Q * 8);
  floatx4 a = pp[0], c = pp[1];
  ushort8 v;
  #pragma unroll
  for (int q = 0; q < 4; ++q) { v[q] = f2bf(a[q]); v[4 + q] = f2bf(c[q]); }
  *(ushort8*)(out + outQ * 8) = v;
}

// ---- transpose W (K x 4096 f32) -> WT' (4096 x K bf16) -------------------
// gate-interleaved rows: n' = (n&1023)*4 + (n>>10); quad-XOR swizzle keyed n'
__global__ __launch_bounds__(256) void transpose_swz(const float* __restrict__ W,
                                                     unsigned short* __restrict__ out, int K) {
  __shared__ unsigned short tile[64 * 65];
  int tid = threadIdx.x;
  int ktiles = K >> 6;
  int kt = blockIdx.x % ktiles;
  int nt = blockIdx.x / ktiles;
  #pragma unroll
  for (int i = 0; i < 16; ++i) {
    int lin = i * 256 + tid;
    int lk = lin >> 6, nn = lin & 63;
    tile[lk * 65 + nn] = f2bf(W[(size_t)(kt * 64 + lk) * 4096 + nt * 64 + nn]);
  }
  __syncthreads();
  #pragma unroll
  for (int it = 0; it < 2; ++it) {
    int idx = it * 256 + tid;
    int nl = idx >> 3, ql = idx & 7;
    int norig = nt * 64 + nl;
    int np = ((norig & 1023) << 2) | (norig >> 10);
    ushort8 v;
    #pragma unroll
    for (int j = 0; j < 8; ++j) v[j] = tile[(ql * 8 + j) * 65 + nl];
    size_t off = (size_t)np * K + (size_t)((kt * 8 + (ql ^ (np & 7))) << 3);
    *(ushort8*)(out + off) = v;
  }
}

// ---- permute biases into gate-interleaved order: bp[u*4+g] = b[g*1024+u] --
__global__ __launch_bounds__(256) void bias_perm(const float* __restrict__ b1,
                                                 const float* __restrict__ b2,
                                                 float* __restrict__ b1p,
                                                 float* __restrict__ b2p) {
  int idx = blockIdx.x * 256 + threadIdx.x;   // 0..8191
  const float* src = (idx < 4096) ? b1 : b2;
  float* dst = (idx < 4096) ? b1p : b2p;
  int n = idx & 4095;
  dst[n] = src[(n & 3) * 1024 + (n >> 2)];
}

// ---------------- fused phase: GEMM + LSTM cell epilogue ------------------
// 256 blocks x 256 thr. layer = bid>>7. Tile 64 rows x 128 WT'-rows
// (= 32 h-units x 4 gates). Double-buffered LDS, all staging via
// global_load_lds (swizzle pre-baked in global layouts).
__global__ __launch_bounds__(256) void gemm_cell(
    const unsigned short* __restrict__ Xbf,
    unsigned short* __restrict__ h1bufs, unsigned short* __restrict__ h2bufs,
    const unsigned short* __restrict__ WT1, const unsigned short* __restrict__ WT2,
    const float* __restrict__ b1p, const float* __restrict__ b2p,
    float* __restrict__ c1, float* __restrict__ c2,
    int p, int do1, int do2) {
  __shared__ __align__(16) char smem[49152];
  unsigned short* Abuf = (unsigned short*)smem;            // [2][64*64]
  unsigned short* Bbuf = (unsigned short*)(smem + 16384);  // [2][128*64]
  float* zt = (float*)smem;                                // [64][132] epilogue

  int bid = blockIdx.x;
  int layer = bid >> 7;
  if (layer == 0 ? !do1 : !do2) return;
  int lid = bid & 127;
  // co-locate the 4 m-blocks of one n-tile on one XCD (bid mod 8 equal)
  int ntile = (lid & 7) | (((lid >> 5) & 3) << 3);
  int mtile = (lid >> 3) & 3;
  int m0 = mtile * 64;
  int n0 = ntile * 128;   // WT' row base
  int u0 = ntile * 32;    // h-unit base

  const unsigned short* hp1 = h1bufs + (size_t)(p & 1) * (BB * HH);
  const unsigned short* hp2 = h2bufs + (size_t)(p & 1) * (BB * HH);
  unsigned short* hn = (layer ? h2bufs : h1bufs) + (size_t)((p + 1) & 1) * (BB * HH);
  const unsigned short* Bw = layer ? WT2 : WT1;
  const int K = layer ? 2048 : 1152;
  const int niter = K >> 6;

  int tid = threadIdx.x;
  int w = tid >> 6, lane = tid & 63;

  floatx4 acc[4][2];
  #pragma unroll
  for (int i = 0; i < 4; ++i)
    #pragma unroll
    for (int j = 0; j < 2; ++j) acc[i][j] = (floatx4){0.f, 0.f, 0.f, 0.f};

  auto stageB = [&](int buf, int k0) {
    unsigned short* base = Bbuf + buf * (128 * 64);
    #pragma unroll
    for (int c = 0; c < 4; ++c) {
      int nl = w * 32 + c * 8;
      const unsigned short* src =
          Bw + (size_t)(n0 + nl + (lane >> 3)) * K + k0 + (lane & 7) * 8;
      GLOAD_LDS16(src, base + nl * 64);
    }
  };
  auto stageA = [&](int buf, int k0) {
    unsigned short* base = Abuf + buf * (64 * 64);
    #pragma unroll
    for (int c = 0; c < 2; ++c) {
      int ml = w * 16 + c * 8;
      int row = m0 + ml + (lane >> 3);
      const unsigned short* src;
      if (layer == 0)
        src = (k0 < DD) ? (Xbf + (size_t)row * TD + p * DD + k0 + (lane & 7) * 8)
                        : (hp1 + (size_t)row * HH + (k0 - DD) + (lane & 7) * 8);
      else
        src = (k0 < HH) ? (hp1 + (size_t)row * HH + k0 + (lane & 7) * 8)
                        : (hp2 + (size_t)row * HH + (k0 - HH) + (lane & 7) * 8);
      GLOAD_LDS16(src, base + ml * 64);
    }
  };

  stageA(0, 0); stageB(0, 0);
  for (int it = 0; it < niter; ++it) {
    int buf = it & 1;
    __syncthreads();  // buf ready (barrier drains vmcnt); prefetch had ~full compute to land
    if (it + 1 < niter) { stageA(buf ^ 1, (it + 1) << 6); stageB(buf ^ 1, (it + 1) << 6); }
    const unsigned short* Ab = Abuf + buf * (64 * 64);
    const unsigned short* Bb = Bbuf + buf * (128 * 64);
    #pragma unroll
    for (int ks = 0; ks < 2; ++ks) {
      int qb = ks * 4 + (lane >> 4);
      short8 af[4], bfv[2];
      #pragma unroll
      for (int mi = 0; mi < 4; ++mi) {
        int ml = mi * 16 + (lane & 15);
        af[mi] = *(const short8*)&Ab[ml * 64 + ((qb ^ (ml & 7)) << 3)];
      }
      #pragma unroll
      for (int ni = 0; ni < 2; ++ni) {
        int nl = w * 32 + ni * 16 + (lane & 15);
        bfv[ni] = *(const short8*)&Bb[nl * 64 + ((qb ^ (nl & 7)) << 3)];
      }
      #pragma unroll
      for (int mi = 0; mi < 4; ++mi)
        #pragma unroll
        for (int ni = 0; ni < 2; ++ni)
          acc[mi][ni] = __builtin_amdgcn_mfma_f32_16x16x32_bf16(af[mi], bfv[ni],
                                                                acc[mi][ni], 0, 0, 0);
    }
  }
  __syncthreads();  // done reading staging LDS; reuse as zt

  // acc -> zt (C/D layout: col=lane&15, row=(lane>>4)*4+rr)
  #pragma unroll
  for (int mi = 0; mi < 4; ++mi)
    #pragma unroll
    for (int ni = 0; ni < 2; ++ni)
      #pragma unroll
      for (int rr = 0; rr < 4; ++rr) {
        int row = mi * 16 + (lane >> 4) * 4 + rr;
        int col = w * 32 + ni * 16 + (lane & 15);
        zt[row * 132 + col] = acc[mi][ni][rr];
      }
  __syncthreads();

  // cell: thread -> (row r = tid>>2, unit group ug = tid&3 -> 8 units)
  int r = tid >> 2, ug = tid & 3;
  int rg = m0 + r;
  float* cp = (layer ? c2 : c1) + (size_t)rg * HH + u0 + ug * 8;
  const float* bp = (layer ? b2p : b1p) + (size_t)(u0 + ug * 8) * 4;
  floatx4 cold0 = *(const floatx4*)cp;
  floatx4 cold1 = *(const floatx4*)(cp + 4);
  floatx4 cn0, cn1;
  ushort8 hv;
  #pragma unroll
  for (int k = 0; k < 8; ++k) {
    floatx4 g = *(const floatx4*)&zt[r * 132 + (ug * 8 + k) * 4];
    floatx4 bb = *(const floatx4*)&bp[k * 4];
    float i_ = g[0] + bb[0];
    float j_ = g[1] + bb[1];
    float f_ = g[2] + bb[2] + 1.f;   // FORGET_BIAS
    float o_ = g[3] + bb[3];
    float cv = (k < 4) ? cold0[k & 3] : cold1[k & 3];
    float nc = cv * sigm(f_) + sigm(i_) * tanh_fast(j_);
    if (k < 4) cn0[k & 3] = nc; else cn1[k & 3] = nc;
    hv[k] = f2bf(tanh_fast(nc) * sigm(o_));
  }
  *(floatx4*)cp = cn0;
  *(floatx4*)(cp + 4) = cn1;
  int q = (u0 >> 3) + ug;   // h quad index; swizzle keyed by batch row
  *(ushort8*)&hn[(size_t)rg * HH + ((q & ~7) << 3) + (((q ^ rg) & 7) << 3)] = hv;
}

// ---------------- dense head + MSE loss (h2 is swizzled) ------------------
__global__ __launch_bounds__(64) void head_loss(const unsigned short* __restrict__ h2,
                                                const float* __restrict__ Wd,
                                                const float* __restrict__ bd,
                                                const float* __restrict__ labels,
                                                float* __restrict__ out) {
  int b = blockIdx.x;
  int l = threadIdx.x;
  float pacc[24];
  #pragma unroll
  for (int n = 0; n < 24; ++n) pacc[n] = 0.f;
  for (int k = l; k < HH; k += 64) {
    int ksw = (k & ~63) | ((((k >> 3) ^ b) & 7) << 3) | (k & 7);
    float hv = bf2f(h2[(size_t)b * HH + ksw]);
    const float* wr = Wd + (size_t)k * 24;
    #pragma unroll
    for (int n = 0; n < 24; ++n) pacc[n] += hv * wr[n];
  }
  #pragma unroll
  for (int n = 0; n < 24; ++n) {
    float v = pacc[n];
    for (int off = 32; off > 0; off >>= 1) v += __shfl_down(v, off);
    pacc[n] = v;
  }
  if (l == 0) {
    float s = 0.f;
    #pragma unroll
    for (int n = 0; n < 24; ++n) {
      float pred = pacc[n] + bd[n];
      float d = pred - labels[b * 24 + n];
      s += d * d;
    }
    atomicAdd(out, s * (1.0f / 6144.0f));
  }
}

extern "C" void kernel_launch(void* const* d_in, const int* in_sizes, int n_in,
                              void* d_out, int out_size, void* d_ws, size_t ws_size,
                              hipStream_t stream) {
  const float* features = (const float*)d_in[0];
  const float* labels   = (const float*)d_in[1];
  const float* W1 = (const float*)d_in[2];
  const float* b1 = (const float*)d_in[3];
  const float* W2 = (const float*)d_in[4];
  const float* b2 = (const float*)d_in[5];
  const float* Wd = (const float*)d_in[6];
  const float* bd = (const float*)d_in[7];

  char* ws = (char*)d_ws;
  float*          c1  = (float*)(ws + OFF_C1);
  float*          c2  = (float*)(ws + OFF_C2);
  unsigned short* h1  = (unsigned short*)(ws + OFF_H1);
  unsigned short* h2  = (unsigned short*)(ws + OFF_H2);
  float*          b1p = (float*)(ws + OFF_B1P);
  float*          b2p = (float*)(ws + OFF_B2P);
  unsigned short* Xbf = (unsigned short*)(ws + OFF_X);
  unsigned short* WT1 = (unsigned short*)(ws + OFF_W1T);
  unsigned short* WT2 = (unsigned short*)(ws + OFF_W2T);
  float* out = (float*)d_out;

  init_zero<<<1024, 256, 0, stream>>>(out, (uint4*)ws, 262144L);
  feat2bf<<<5376, 256, 0, stream>>>(features, Xbf, 1376256L);
  transpose_swz<<<18 * 64, 256, 0, stream>>>(W1, WT1, 1152);
  transpose_swz<<<32 * 64, 256, 0, stream>>>(W2, WT2, 2048);
  bias_perm<<<32, 256, 0, stream>>>(b1, b2, b1p, b2p);

  // phase p: layer0 computes h1(p) [p<T]; layer1 computes h2(p-1) [p>=1]
  for (int p = 0; p <= TT; ++p) {
    gemm_cell<<<256, 256, 0, stream>>>(Xbf, h1, h2, WT1, WT2, b1p, b2p, c1, c2,
                                       p, p < TT ? 1 : 0, p >= 1 ? 1 : 0);
  }
  // final h2 is buffer (T+1)&1 = 1
  head_loss<<<256, 64, 0, stream>>>(h2 + 262144, Wd, bd, labels, out);
}